// Round 1
// baseline (376.063 us; speedup 1.0000x reference)
//
#include <hip/hip_runtime.h>
#include <cmath>

#define NN 50000
#define KK 15
#define DD 128
#define HH 64
#define NKE (NN * KK)

// ---------------------------------------------------------------------------
// Kernel P: precompute per-node partial matmuls.
//   XA = x @ ew1[0:128,:]      (dst contribution to edge layer 1)
//   XB = x @ ew1[128:256,:]    (src contribution to edge layer 1)
//   XC = x @ dw1[0:128,:]      (node contribution to degree layer 1)
// Thread-per-row; x row held in 128 VGPRs; weight indices are wave-uniform so
// the compiler emits s_load_dwordx4 (scalar pipe) -> inner loop is pure VALU.
// ---------------------------------------------------------------------------
__global__ __launch_bounds__(256) void kP(const float* __restrict__ x,
                                          const float* __restrict__ ew1,
                                          const float* __restrict__ dw1,
                                          float* __restrict__ ws) {
    const int nblk = (NN + 255) / 256;
    int seg = blockIdx.x / nblk;
    int row = (blockIdx.x - seg * nblk) * 256 + threadIdx.x;
    if (row >= NN) return;
    const float* W;
    float* out;
    if (seg == 0)      { W = ew1;            out = ws; }
    else if (seg == 1) { W = ew1 + 128 * HH; out = ws + (size_t)NN * HH; }
    else               { W = dw1;            out = ws + 2 * (size_t)NN * HH; }

    float xr[DD];
    const float4* xv = (const float4*)(x + (size_t)row * DD);
#pragma unroll
    for (int i = 0; i < DD / 4; ++i) {
        float4 v = xv[i];
        xr[4 * i + 0] = v.x; xr[4 * i + 1] = v.y;
        xr[4 * i + 2] = v.z; xr[4 * i + 3] = v.w;
    }
    float* orow = out + (size_t)row * HH;
#pragma unroll 1
    for (int jj = 0; jj < HH / 4; ++jj) {
        float ax = 0.f, ay = 0.f, az = 0.f, aw = 0.f;
#pragma unroll
        for (int k = 0; k < DD; ++k) {
            float4 w = *(const float4*)(W + k * HH + jj * 4);
            float xk = xr[k];
            ax = fmaf(xk, w.x, ax); ay = fmaf(xk, w.y, ay);
            az = fmaf(xk, w.z, az); aw = fmaf(xk, w.w, aw);
        }
        float4 o; o.x = ax; o.y = ay; o.z = az; o.w = aw;
        *(float4*)(orow + jj * 4) = o;
    }
}

// ---------------------------------------------------------------------------
// Kernel E: thread-per-edge. h1 = relu(XA[dst]+XB[src]+dist*w1_last+b1) in
// 64 VGPRs, then 64x64 layer-2 matvec (scalar-loaded weights) + 64-dot layer 3
// -> edge_energy written directly into d_out[2*NKE ..].
// ---------------------------------------------------------------------------
__global__ __launch_bounds__(256) void kE(const int* __restrict__ srcIdx,
                                          const float* __restrict__ dist,
                                          const float* __restrict__ ws,
                                          const float* __restrict__ ew1,
                                          const float* __restrict__ eb1,
                                          const float* __restrict__ ew2,
                                          const float* __restrict__ eb2,
                                          const float* __restrict__ ew3,
                                          const float* __restrict__ eb3,
                                          float* __restrict__ energy_out) {
    int e = blockIdx.x * 256 + threadIdx.x;
    if (e >= NKE) return;
    int s = srcIdx[e];
    int d = e / KK;
    float dd = dist[e];
    const float4* a4 = (const float4*)(ws + (size_t)d * HH);
    const float4* b4 = (const float4*)(ws + (size_t)NN * HH + (size_t)s * HH);
    const float* w1l = ew1 + 256 * HH;

    float h1[HH];
#pragma unroll
    for (int c = 0; c < HH / 4; ++c) {
        float4 a = a4[c];
        float4 b = b4[c];
        float4 w = *(const float4*)(w1l + 4 * c);
        float4 bb = *(const float4*)(eb1 + 4 * c);
        h1[4 * c + 0] = fmaxf(a.x + b.x + dd * w.x + bb.x, 0.f);
        h1[4 * c + 1] = fmaxf(a.y + b.y + dd * w.y + bb.y, 0.f);
        h1[4 * c + 2] = fmaxf(a.z + b.z + dd * w.z + bb.z, 0.f);
        h1[4 * c + 3] = fmaxf(a.w + b.w + dd * w.w + bb.w, 0.f);
    }
    float logit = eb3[0];
#pragma unroll 1
    for (int jj = 0; jj < HH / 4; ++jj) {
        float4 acc = *(const float4*)(eb2 + jj * 4);
#pragma unroll
        for (int i = 0; i < HH; ++i) {
            float4 w = *(const float4*)(ew2 + i * HH + jj * 4);
            float hv = h1[i];
            acc.x = fmaf(hv, w.x, acc.x);
            acc.y = fmaf(hv, w.y, acc.y);
            acc.z = fmaf(hv, w.z, acc.z);
            acc.w = fmaf(hv, w.w, acc.w);
        }
        float4 w3 = *(const float4*)(ew3 + jj * 4);
        logit = fmaf(fmaxf(acc.x, 0.f), w3.x, logit);
        logit = fmaf(fmaxf(acc.y, 0.f), w3.y, logit);
        logit = fmaf(fmaxf(acc.z, 0.f), w3.z, logit);
        logit = fmaf(fmaxf(acc.w, 0.f), w3.w, logit);
    }
    // energy = sigmoid(logit / 0.5)
    energy_out[e] = 1.f / (1.f + expf(-2.f * logit));
}

// ---------------------------------------------------------------------------
// Kernel F: thread-per-node. degree hint, node MLP -> k_cont, register-resident
// Batcher-16 sorting network (descending energy, stable by index), hard gate,
// normalize, scatter through inverse permutation. Writes edge_weight,
// edge_gate, k_cont.
// ---------------------------------------------------------------------------
__global__ __launch_bounds__(256) void kF(const float* __restrict__ ws,
                                          const float* __restrict__ dw1,
                                          const float* __restrict__ db1,
                                          const float* __restrict__ dw2,
                                          const float* __restrict__ db2,
                                          const float* __restrict__ dw3,
                                          const float* __restrict__ db3,
                                          float* __restrict__ out) {
    int n = blockIdx.x * 256 + threadIdx.x;
    if (n >= NN) return;
    const float* energy = out + 2 * (size_t)NKE;

    float ev[KK];
    float dh = 0.f;
#pragma unroll
    for (int j = 0; j < KK; ++j) {
        ev[j] = energy[(size_t)n * KK + j];
        dh += ev[j];
    }

    // node MLP layer 1: relu(XC[n] + dh * dw1_last + db1)
    const float4* c4 = (const float4*)(ws + 2 * (size_t)NN * HH + (size_t)n * HH);
    const float* w1l = dw1 + 128 * HH;
    float g1[HH];
#pragma unroll
    for (int c = 0; c < HH / 4; ++c) {
        float4 a = c4[c];
        float4 w = *(const float4*)(w1l + 4 * c);
        float4 bb = *(const float4*)(db1 + 4 * c);
        g1[4 * c + 0] = fmaxf(a.x + dh * w.x + bb.x, 0.f);
        g1[4 * c + 1] = fmaxf(a.y + dh * w.y + bb.y, 0.f);
        g1[4 * c + 2] = fmaxf(a.z + dh * w.z + bb.z, 0.f);
        g1[4 * c + 3] = fmaxf(a.w + dh * w.w + bb.w, 0.f);
    }
    float kraw = db3[0];
#pragma unroll 1
    for (int jj = 0; jj < HH / 4; ++jj) {
        float4 acc = *(const float4*)(db2 + jj * 4);
#pragma unroll
        for (int i = 0; i < HH; ++i) {
            float4 w = *(const float4*)(dw2 + i * HH + jj * 4);
            float hv = g1[i];
            acc.x = fmaf(hv, w.x, acc.x);
            acc.y = fmaf(hv, w.y, acc.y);
            acc.z = fmaf(hv, w.z, acc.z);
            acc.w = fmaf(hv, w.w, acc.w);
        }
        float4 w3 = *(const float4*)(dw3 + jj * 4);
        kraw = fmaf(fmaxf(acc.x, 0.f), w3.x, kraw);
        kraw = fmaf(fmaxf(acc.y, 0.f), w3.y, kraw);
        kraw = fmaf(fmaxf(acc.z, 0.f), w3.z, kraw);
        kraw = fmaf(fmaxf(acc.w, 0.f), w3.w, kraw);
    }
    float kcont = 2.f + 13.f / (1.f + expf(-kraw));
    out[3 * (size_t)NKE + n] = kcont;

    // ---- register-resident sort of (energy desc, idx asc), 16-wide network
    float se[16];
    int si[16];
#pragma unroll
    for (int j = 0; j < KK; ++j) { se[j] = ev[j]; si[j] = j; }
    se[15] = -1.f; si[15] = 15;   // padding, sorts to the end

#pragma unroll
    for (int p = 1; p < 16; p <<= 1) {
#pragma unroll
        for (int k = p; k >= 1; k >>= 1) {
#pragma unroll
            for (int j = k & (p - 1); j + k < 16; j += 2 * k) {
#pragma unroll
                for (int i = 0; i < k; ++i) {
                    int a = i + j, b = i + j + k;
                    if (b < 16 && (a / (2 * p)) == (b / (2 * p))) {
                        // keep the (larger energy, smaller idx) at position a
                        bool sw = (se[b] > se[a]) ||
                                  (se[b] == se[a] && si[b] < si[a]);
                        float ea = sw ? se[b] : se[a];
                        float eb = sw ? se[a] : se[b];
                        int ia = sw ? si[b] : si[a];
                        int ib = sw ? si[a] : si[b];
                        se[a] = ea; se[b] = eb; si[a] = ia; si[b] = ib;
                    }
                }
            }
        }
    }

    // hard gate: forward value of the straight-through gate is exactly gate_hard
    float kint = rintf(kcont);              // round-half-even, matches np.round
    kint = fminf(fmaxf(kint, 2.f), 15.f);

    float wsrt[KK];
    float denom = 0.f;
#pragma unroll
    for (int r = 0; r < KK; ++r) {
        float sel = ((float)(r + 1) <= kint) ? 1.f : 0.f;
        float wv = se[r] * sel;
        wsrt[r] = wv;
        denom += wv;
    }
    denom = fmaxf(denom, 1e-12f);

#pragma unroll
    for (int r = 0; r < KK; ++r) {
        float sel = ((float)(r + 1) <= kint) ? 1.f : 0.f;
        int j0 = si[r];
        out[(size_t)NKE + (size_t)n * KK + j0] = sel;           // edge_gate
        out[(size_t)n * KK + j0] = wsrt[r] / denom;             // edge_weight
    }
}

extern "C" void kernel_launch(void* const* d_in, const int* in_sizes, int n_in,
                              void* d_out, int out_size, void* d_ws, size_t ws_size,
                              hipStream_t stream) {
    const float* x   = (const float*)d_in[0];
    const int*   ei  = (const int*)d_in[1];   // row 0 = src, row 1 = dst
    const float* ed  = (const float*)d_in[2];
    const float* ew1 = (const float*)d_in[3];
    const float* eb1 = (const float*)d_in[4];
    const float* ew2 = (const float*)d_in[5];
    const float* eb2 = (const float*)d_in[6];
    const float* ew3 = (const float*)d_in[7];
    const float* eb3 = (const float*)d_in[8];
    const float* dw1 = (const float*)d_in[9];
    const float* db1 = (const float*)d_in[10];
    const float* dw2 = (const float*)d_in[11];
    const float* db2 = (const float*)d_in[12];
    const float* dw3 = (const float*)d_in[13];
    const float* db3 = (const float*)d_in[14];
    float* out = (float*)d_out;
    float* ws  = (float*)d_ws;

    const int nblkN = (NN + 255) / 256;           // 196
    const int nblkE = (NKE + 255) / 256;          // 2930

    hipLaunchKernelGGL(kP, dim3(3 * nblkN), dim3(256), 0, stream, x, ew1, dw1, ws);
    hipLaunchKernelGGL(kE, dim3(nblkE), dim3(256), 0, stream,
                       ei, ed, ws, ew1, eb1, ew2, eb2, ew3, eb3,
                       out + 2 * (size_t)NKE);
    hipLaunchKernelGGL(kF, dim3(nblkN), dim3(256), 0, stream,
                       ws, dw1, db1, dw2, db2, dw3, db3, out);
}

// Round 2
// 325.227 us; speedup vs baseline: 1.1563x; 1.1563x over previous
//
#include <hip/hip_runtime.h>
#include <cmath>

#define NN 50000
#define KK 15
#define DD 128
#define HH 64
#define NKE (NN * KK)

// ---------------------------------------------------------------------------
// kP: ws[seg][row][j] = x[row] @ W_seg
//   seg0 = ew1[0:128]   (XA, dst contribution)
//   seg1 = ew1[128:256] (XB, src contribution)
//   seg2 = dw1[0:128]   (XC, node contribution)
// One wave = 8 rows x 64 output cols (lane = j).
//   x   : wave-uniform addresses -> s_load (scalar pipe)
//   W   : lane-consecutive dword loads (coalesced, L1-resident 32 KB)
//   out : lane-consecutive stores (full 256 B lines -> no write-allocate)
// ---------------------------------------------------------------------------
__global__ __launch_bounds__(256) void kP(const float* __restrict__ x,
                                          const float* __restrict__ ew1,
                                          const float* __restrict__ dw1,
                                          float* __restrict__ ws) {
    int lane = threadIdx.x & 63;
    int wv = __builtin_amdgcn_readfirstlane((int)(threadIdx.x >> 6));
    int seg = blockIdx.y;
    int rb = blockIdx.x * 32 + wv * 8;       // 8 rows per wave; NN % 8 == 0
    if (rb >= NN) return;
    const float* W = (seg == 0) ? ew1 : (seg == 1) ? (ew1 + 128 * HH) : dw1;
    const float* xw = x + (size_t)rb * DD;

    float acc[8];
#pragma unroll
    for (int r = 0; r < 8; ++r) acc[r] = 0.f;

#pragma unroll 1
    for (int i4 = 0; i4 < DD / 4; ++i4) {
        // 8 wave-uniform float4 x loads (scalar pipe)
        float xv[8][4];
#pragma unroll
        for (int r = 0; r < 8; ++r) {
            float4 v = *(const float4*)(xw + r * DD + i4 * 4);
            xv[r][0] = v.x; xv[r][1] = v.y; xv[r][2] = v.z; xv[r][3] = v.w;
        }
#pragma unroll
        for (int k = 0; k < 4; ++k) {
            float w = W[(i4 * 4 + k) * HH + lane];   // coalesced 256B/inst
#pragma unroll
            for (int r = 0; r < 8; ++r)
                acc[r] = fmaf(xv[r][k], w, acc[r]);
        }
    }
    float* o = ws + (size_t)seg * NN * HH + (size_t)rb * HH + lane;
#pragma unroll
    for (int r = 0; r < 8; ++r) o[r * HH] = acc[r];   // coalesced
}

// ---------------------------------------------------------------------------
// kE: 2 edges per thread, accumulator-resident (no h1 array -> no spill).
// h computed per-i and immediately FMA'd into acc0[64]/acc1[64].
// Weights via wave-uniform global reads -> s_load on the scalar pipe.
// ---------------------------------------------------------------------------
__global__ __launch_bounds__(256, 1) void kE(const int* __restrict__ srcIdx,
                                             const float* __restrict__ dist,
                                             const float* __restrict__ ws,
                                             const float* __restrict__ ew1,
                                             const float* __restrict__ eb1,
                                             const float* __restrict__ ew2,
                                             const float* __restrict__ eb2,
                                             const float* __restrict__ ew3,
                                             const float* __restrict__ eb3,
                                             float* __restrict__ energy_out) {
    int t = blockIdx.x * 256 + threadIdx.x;
    int e0 = t * 2;
    if (e0 >= NKE) return;
    int s0 = srcIdx[e0], s1 = srcIdx[e0 + 1];
    int d0 = e0 / KK, d1 = (e0 + 1) / KK;
    float di0 = dist[e0], di1 = dist[e0 + 1];
    const float4* XA = (const float4*)ws;
    const float4* XB = (const float4*)(ws + (size_t)NN * HH);
    const float* w1l = ew1 + 2 * DD * HH;   // row 256: dist weights

    float acc0[HH], acc1[HH];
#pragma unroll
    for (int j = 0; j < HH; ++j) { acc0[j] = 0.f; acc1[j] = 0.f; }

#pragma unroll 1
    for (int i4 = 0; i4 < HH / 4; ++i4) {
        float4 a0 = XA[d0 * 16 + i4], b0 = XB[s0 * 16 + i4];
        float4 a1 = XA[d1 * 16 + i4], b1 = XB[s1 * 16 + i4];
        float av0[4] = {a0.x, a0.y, a0.z, a0.w};
        float bv0[4] = {b0.x, b0.y, b0.z, b0.w};
        float av1[4] = {a1.x, a1.y, a1.z, a1.w};
        float bv1[4] = {b1.x, b1.y, b1.z, b1.w};
        float h0[4], h1v[4];
#pragma unroll
        for (int k = 0; k < 4; ++k) {
            float wl = w1l[i4 * 4 + k];     // uniform -> s_load
            float bb = eb1[i4 * 4 + k];
            h0[k]  = fmaxf(av0[k] + bv0[k] + di0 * wl + bb, 0.f);
            h1v[k] = fmaxf(av1[k] + bv1[k] + di1 * wl + bb, 0.f);
        }
#pragma unroll
        for (int k = 0; k < 4; ++k) {
            const float* wr = ew2 + (i4 * 4 + k) * HH;   // uniform row
#pragma unroll
            for (int jj = 0; jj < 16; ++jj) {
                acc0[jj * 4 + 0] = fmaf(h0[k], wr[jj * 4 + 0], acc0[jj * 4 + 0]);
                acc0[jj * 4 + 1] = fmaf(h0[k], wr[jj * 4 + 1], acc0[jj * 4 + 1]);
                acc0[jj * 4 + 2] = fmaf(h0[k], wr[jj * 4 + 2], acc0[jj * 4 + 2]);
                acc0[jj * 4 + 3] = fmaf(h0[k], wr[jj * 4 + 3], acc0[jj * 4 + 3]);
                acc1[jj * 4 + 0] = fmaf(h1v[k], wr[jj * 4 + 0], acc1[jj * 4 + 0]);
                acc1[jj * 4 + 1] = fmaf(h1v[k], wr[jj * 4 + 1], acc1[jj * 4 + 1]);
                acc1[jj * 4 + 2] = fmaf(h1v[k], wr[jj * 4 + 2], acc1[jj * 4 + 2]);
                acc1[jj * 4 + 3] = fmaf(h1v[k], wr[jj * 4 + 3], acc1[jj * 4 + 3]);
            }
        }
    }
    float lg0 = eb3[0], lg1 = eb3[0];
#pragma unroll
    for (int j = 0; j < HH; ++j) {
        float b2 = eb2[j], w3 = ew3[j];
        lg0 = fmaf(fmaxf(acc0[j] + b2, 0.f), w3, lg0);
        lg1 = fmaf(fmaxf(acc1[j] + b2, 0.f), w3, lg1);
    }
    float2 en;
    en.x = 1.f / (1.f + expf(-2.f * lg0));
    en.y = 1.f / (1.f + expf(-2.f * lg1));
    *(float2*)(energy_out + e0) = en;
}

// ---------------------------------------------------------------------------
// kF: thread-per-node, accumulator-resident node MLP (no g1 spill), then the
// register sorting network + hard top-k gate + normalize + scatter.
// ---------------------------------------------------------------------------
__global__ __launch_bounds__(128, 1) void kF(const float* __restrict__ ws,
                                             const float* __restrict__ dw1,
                                             const float* __restrict__ db1,
                                             const float* __restrict__ dw2,
                                             const float* __restrict__ db2,
                                             const float* __restrict__ dw3,
                                             const float* __restrict__ db3,
                                             float* __restrict__ out) {
    int n = blockIdx.x * 128 + threadIdx.x;
    if (n >= NN) return;
    const float* energy = out + 2 * (size_t)NKE;

    float ev[KK];
    float dh = 0.f;
#pragma unroll
    for (int j = 0; j < KK; ++j) {
        ev[j] = energy[(size_t)n * KK + j];
        dh += ev[j];
    }

    const float4* XC = (const float4*)(ws + 2 * (size_t)NN * HH);
    const float* w1l = dw1 + DD * HH;   // row 128: degree-hint weights

    float acc[HH];
#pragma unroll
    for (int j = 0; j < HH; ++j) acc[j] = 0.f;

#pragma unroll 1
    for (int i4 = 0; i4 < HH / 4; ++i4) {
        float4 c = XC[n * 16 + i4];
        float cv[4] = {c.x, c.y, c.z, c.w};
#pragma unroll
        for (int k = 0; k < 4; ++k) {
            float g = fmaxf(cv[k] + dh * w1l[i4 * 4 + k] + db1[i4 * 4 + k], 0.f);
            const float* wr = dw2 + (i4 * 4 + k) * HH;
#pragma unroll
            for (int jj = 0; jj < 16; ++jj) {
                acc[jj * 4 + 0] = fmaf(g, wr[jj * 4 + 0], acc[jj * 4 + 0]);
                acc[jj * 4 + 1] = fmaf(g, wr[jj * 4 + 1], acc[jj * 4 + 1]);
                acc[jj * 4 + 2] = fmaf(g, wr[jj * 4 + 2], acc[jj * 4 + 2]);
                acc[jj * 4 + 3] = fmaf(g, wr[jj * 4 + 3], acc[jj * 4 + 3]);
            }
        }
    }
    float kraw = db3[0];
#pragma unroll
    for (int j = 0; j < HH; ++j)
        kraw = fmaf(fmaxf(acc[j] + db2[j], 0.f), dw3[j], kraw);

    float kcont = 2.f + 13.f / (1.f + expf(-kraw));
    out[3 * (size_t)NKE + n] = kcont;

    // ---- register-resident sort of (energy desc, idx asc), 16-wide network
    float se[16];
    int si[16];
#pragma unroll
    for (int j = 0; j < KK; ++j) { se[j] = ev[j]; si[j] = j; }
    se[15] = -1.f; si[15] = 15;

#pragma unroll
    for (int p = 1; p < 16; p <<= 1) {
#pragma unroll
        for (int k = p; k >= 1; k >>= 1) {
#pragma unroll
            for (int j = k & (p - 1); j + k < 16; j += 2 * k) {
#pragma unroll
                for (int i = 0; i < k; ++i) {
                    int a = i + j, b = i + j + k;
                    if (b < 16 && (a / (2 * p)) == (b / (2 * p))) {
                        bool sw = (se[b] > se[a]) ||
                                  (se[b] == se[a] && si[b] < si[a]);
                        float ea = sw ? se[b] : se[a];
                        float eb = sw ? se[a] : se[b];
                        int ia = sw ? si[b] : si[a];
                        int ib = sw ? si[a] : si[b];
                        se[a] = ea; se[b] = eb; si[a] = ia; si[b] = ib;
                    }
                }
            }
        }
    }

    float kint = rintf(kcont);
    kint = fminf(fmaxf(kint, 2.f), 15.f);

    float wsrt[KK];
    float denom = 0.f;
#pragma unroll
    for (int r = 0; r < KK; ++r) {
        float sel = ((float)(r + 1) <= kint) ? 1.f : 0.f;
        float wv = se[r] * sel;
        wsrt[r] = wv;
        denom += wv;
    }
    denom = fmaxf(denom, 1e-12f);

#pragma unroll
    for (int r = 0; r < KK; ++r) {
        float sel = ((float)(r + 1) <= kint) ? 1.f : 0.f;
        int j0 = si[r];
        out[(size_t)NKE + (size_t)n * KK + j0] = sel;     // edge_gate
        out[(size_t)n * KK + j0] = wsrt[r] / denom;       // edge_weight
    }
}

extern "C" void kernel_launch(void* const* d_in, const int* in_sizes, int n_in,
                              void* d_out, int out_size, void* d_ws, size_t ws_size,
                              hipStream_t stream) {
    const float* x   = (const float*)d_in[0];
    const int*   ei  = (const int*)d_in[1];
    const float* ed  = (const float*)d_in[2];
    const float* ew1 = (const float*)d_in[3];
    const float* eb1 = (const float*)d_in[4];
    const float* ew2 = (const float*)d_in[5];
    const float* eb2 = (const float*)d_in[6];
    const float* ew3 = (const float*)d_in[7];
    const float* eb3 = (const float*)d_in[8];
    const float* dw1 = (const float*)d_in[9];
    const float* db1 = (const float*)d_in[10];
    const float* dw2 = (const float*)d_in[11];
    const float* db2 = (const float*)d_in[12];
    const float* dw3 = (const float*)d_in[13];
    const float* db3 = (const float*)d_in[14];
    float* out = (float*)d_out;
    float* ws  = (float*)d_ws;

    // kP: 32 rows/block, 3 segments on gridDim.y
    hipLaunchKernelGGL(kP, dim3((NN + 31) / 32, 3), dim3(256), 0, stream,
                       x, ew1, dw1, ws);
    // kE: 2 edges/thread
    hipLaunchKernelGGL(kE, dim3((NKE / 2 + 255) / 256), dim3(256), 0, stream,
                       ei, ed, ws, ew1, eb1, ew2, eb2, ew3, eb3,
                       out + 2 * (size_t)NKE);
    // kF: thread-per-node
    hipLaunchKernelGGL(kF, dim3((NN + 127) / 128), dim3(128), 0, stream,
                       ws, dw1, db1, dw2, db2, dw3, db3, out);
}